// Round 6
// baseline (30.294 us; speedup 1.0000x reference)
//
#include <hip/hip_runtime.h>

// GAE backward recurrence, v5 (values re-read eliminated via lane shuffle).
//   adv[t] = delta[t] + c[t] * adv[t+1],  c[t] = (1-first[t+1])*gamma*lambda
//   delta[t] = r[t] + (1-first[t+1])*gamma*V[t+1] - V[t]
// One block per env (4096 blocks x 256 threads).
// Model: kernel is aggregate logical-byte-throughput-bound (~6.4 TB/s R+W,
// = m13 copy ceiling). v4 moved 192MB logical; this version moves the
// compulsory 160MB: r(32)+v(32)+f(32) reads + adv/vtarg(64) writes.
//  Phase 1: coalesced vector loads; v[t+1..t+4] built from v[t..t+3] via
//           __shfl_down (lane 63 patches with one scalar load). delta/c ->
//           XOR-swizzled LDS granules.
//  Phase 2: per-thread 8-step segment; wave shuffle suffix scan of (A,B);
//           4 wave totals via 16B LDS. 3 barriers.
//  Phase 3: nontemporal coalesced float4 stores of adv and v_targ.

constexpr int NE   = 4096;
constexpr int NT   = 2048;
constexpr int NT1  = 2049;
constexpr float GAMMA  = 0.99f;
constexpr float LAMBDA = 0.95f;
constexpr int TPB = 256;
constexpr int PER = NT / TPB;    // 8 timesteps per thread (phase 2 segment)
constexpr int NQ  = NT / 4;      // 512 float4 granules per env
constexpr int QPT = NQ / TPB;    // 2 granules per thread (phases 1 & 3)

typedef float f32x4 __attribute__((ext_vector_type(4)));
typedef float f32x4u __attribute__((ext_vector_type(4), aligned(4)));  // unaligned ld

__device__ __forceinline__ f32x4 ld4u(const float* p) {
    return (f32x4)*reinterpret_cast<const f32x4u*>(p);
}

// 16B-granule XOR swizzle: <=2-way (free) for both lane-consecutive granule
// access (phases 1/3) and lane-stride-2 granule access (phase 2).
__device__ __forceinline__ int swz(int g) { return g ^ ((g >> 3) & 7); }

__global__ __launch_bounds__(TPB) void gae_kernel(
    const float* __restrict__ rewards,   // [NE, NT]
    const float* __restrict__ values,    // [NE, NT+1]
    const float* __restrict__ first,     // [NE, NT+1]
    float* __restrict__ out)             // [adv(NE*NT), vtarg(NE*NT)]
{
    __shared__ f32x4 d_lds[NQ];   // delta, later adv
    __shared__ f32x4 c_lds[NQ];   // decay coefficient
    __shared__ float sWA[4];      // per-wave scan totals
    __shared__ float sWB[4];

    const int e    = blockIdx.x;
    const int tid  = threadIdx.x;
    const int lane = tid & 63;
    const int w    = tid >> 6;

    const float* r_row = rewards + (size_t)e * NT;
    const float* v_row = values  + (size_t)e * NT1;
    const float* f_row = first   + (size_t)e * NT1;

    // ---- Phase 1: vector loads, delta/c into swizzled LDS ----
    f32x4 vreg[QPT];
#pragma unroll
    for (int j = 0; j < QPT; ++j) {
        const int q = j * TPB + tid;
        const int t = 4 * q;
        const f32x4 r4  = *reinterpret_cast<const f32x4*>(r_row + t);  // 16B aligned
        const f32x4 v4a = ld4u(v_row + t);       // v[t..t+3]
        const f32x4 f4  = ld4u(f_row + t + 1);   // f[t+1..t+4]
        // v[t+4] = next lane's v4a.x; lane 63's neighbor is in another wave ->
        // patch with a scalar load (1/64 threads).
        float vnext = __shfl_down(v4a.x, 1);
        if (lane == 63) vnext = v_row[t + 4];
        f32x4 v4b; v4b.x = v4a.y; v4b.y = v4a.z; v4b.z = v4a.w; v4b.w = vnext;
        vreg[j] = v4a;
        const f32x4 nl = 1.0f - f4;
        const f32x4 d4 = r4 + nl * GAMMA * v4b - v4a;
        const f32x4 c4 = nl * (GAMMA * LAMBDA);
        d_lds[swz(q)] = d4;
        c_lds[swz(q)] = c4;
    }
    __syncthreads();

    // ---- Phase 2: per-thread contiguous 8-step segment ----
    float d[PER], c[PER];
    {
        const f32x4 da = d_lds[swz(2 * tid)];
        const f32x4 db = d_lds[swz(2 * tid + 1)];
        const f32x4 ca = c_lds[swz(2 * tid)];
        const f32x4 cb = c_lds[swz(2 * tid + 1)];
        d[0]=da.x; d[1]=da.y; d[2]=da.z; d[3]=da.w;
        d[4]=db.x; d[5]=db.y; d[6]=db.z; d[7]=db.w;
        c[0]=ca.x; c[1]=ca.y; c[2]=ca.z; c[3]=ca.w;
        c[4]=cb.x; c[5]=cb.y; c[6]=cb.z; c[7]=cb.w;
    }

    // Local linear function: x -> A*x + B (incoming adv -> adv at segment head)
    float A = 1.0f, B = 0.0f;
#pragma unroll
    for (int k = PER - 1; k >= 0; --k) {
        B = fmaf(c[k], B, d[k]);
        A *= c[k];
    }

    // Wave-level inclusive suffix scan via shuffles (no barriers).
    float cA = A, cB = B;
#pragma unroll
    for (int off = 1; off < 64; off <<= 1) {
        const float a2 = __shfl_down(cA, off);
        const float b2 = __shfl_down(cB, off);
        if (lane + off < 64) {
            cB = fmaf(cA, b2, cB);
            cA = cA * a2;
        }
    }

    // Wave totals -> LDS (lane 0 holds the whole-wave composition).
    if (lane == 0) { sWA[w] = cA; sWB[w] = cB; }

    // Exclusive-within-wave (suffix from lane+1).
    float EA = __shfl_down(cA, 1);
    float EB = __shfl_down(cB, 1);
    if (lane == 63) { EA = 1.0f; EB = 0.0f; }

    __syncthreads();

    // Tail composition of later waves: T = W_{w+1} o W_{w+2} o W_{w+3}.
    float TB = 0.0f;
    for (int u = 3; u > w; --u) {
        TB = fmaf(sWA[u], TB, sWB[u]);
    }
    // Incoming adv for this thread's segment: (E o T)(0) = EA*TB + EB
    float x = fmaf(EA, TB, EB);

    // Replay local recurrence; stash adv back into d_lds (own slots only).
    float adv[PER];
#pragma unroll
    for (int k = PER - 1; k >= 0; --k) {
        x = fmaf(c[k], x, d[k]);
        adv[k] = x;
    }
    {
        f32x4 a0; a0.x=adv[0]; a0.y=adv[1]; a0.z=adv[2]; a0.w=adv[3];
        f32x4 a1; a1.x=adv[4]; a1.y=adv[5]; a1.z=adv[6]; a1.w=adv[7];
        d_lds[swz(2 * tid)]     = a0;
        d_lds[swz(2 * tid + 1)] = a1;
    }
    __syncthreads();

    // ---- Phase 3: nontemporal coalesced float4 stores ----
    float* __restrict__ adv_out = out + (size_t)e * NT;
    float* __restrict__ vt_out  = out + (size_t)NE * NT + (size_t)e * NT;
#pragma unroll
    for (int j = 0; j < QPT; ++j) {
        const int q = j * TPB + tid;
        const int t = 4 * q;
        const f32x4 a4 = d_lds[swz(q)];
        const f32x4 vt = vreg[j] + a4;
        __builtin_nontemporal_store(a4, reinterpret_cast<f32x4*>(adv_out + t));
        __builtin_nontemporal_store(vt, reinterpret_cast<f32x4*>(vt_out + t));
    }
}

extern "C" void kernel_launch(void* const* d_in, const int* in_sizes, int n_in,
                              void* d_out, int out_size, void* d_ws, size_t ws_size,
                              hipStream_t stream) {
    const float* rewards = (const float*)d_in[0];
    const float* values  = (const float*)d_in[1];
    const float* first   = (const float*)d_in[2];
    float* out = (float*)d_out;
    gae_kernel<<<NE, TPB, 0, stream>>>(rewards, values, first, out);
}